// Round 6
// baseline (533.913 us; speedup 1.0000x reference)
//
#include <hip/hip_runtime.h>
#include <hip/hip_bf16.h>

typedef __hip_bfloat16 bf16;
typedef __attribute__((ext_vector_type(8))) short bshort8;  // 8 x bf16 (4 VGPRs)
typedef __attribute__((ext_vector_type(4))) float f32x4;    // MFMA accumulator

#define GLL16(gsrc, ldst)                                                      \
  __builtin_amdgcn_global_load_lds(                                            \
      (const __attribute__((address_space(1))) void*)(gsrc),                   \
      (__attribute__((address_space(3))) void*)(ldst), 16, 0, 0)

#define MEMFENCE asm volatile("" ::: "memory")
#define BARRIER                                                                \
  do {                                                                         \
    MEMFENCE;                                                                  \
    __builtin_amdgcn_s_barrier();                                              \
    MEMFENCE;                                                                  \
  } while (0)
#define WAIT_LGKM0 asm volatile("s_waitcnt lgkmcnt(0)" ::: "memory")
#define WAIT_VM(n) asm volatile("s_waitcnt vmcnt(" #n ")" ::: "memory")

// ---------------- cast f32 -> bf16, vectorized ----------------
__global__ __launch_bounds__(256) void cast_f32_bf16(const float* __restrict__ src,
                                                     bf16* __restrict__ dst, int n4) {
  int stride = gridDim.x * blockDim.x;
  const float4* s4 = reinterpret_cast<const float4*>(src);
  __hip_bfloat162* d2 = reinterpret_cast<__hip_bfloat162*>(dst);
  for (int i = blockIdx.x * blockDim.x + threadIdx.x; i < n4; i += stride) {
    float4 v = s4[i];
    d2[2 * i]     = __float22bfloat162_rn(make_float2(v.x, v.y));
    d2[2 * i + 1] = __float22bfloat162_rn(make_float2(v.z, v.w));
  }
}

// ---------------- x (b,i,m) f32 -> Xt (b,m,i) bf16 ----------------
__global__ __launch_bounds__(256) void transpose_cast_x(const float* __restrict__ x,
                                                        bf16* __restrict__ Xt) {
  __shared__ bf16 t[64][65];
  int b = blockIdx.z;
  int m0 = blockIdx.x * 64;
  int i0 = blockIdx.y * 64;
  int tx = threadIdx.x & 63;
  int ty = threadIdx.x >> 6;
  for (int ii = ty; ii < 64; ii += 4)
    t[ii][tx] = __float2bfloat16(x[(size_t)(b * 256 + i0 + ii) * 4096 + m0 + tx]);
  __syncthreads();
  for (int mm = ty; mm < 64; mm += 4)
    Xt[(size_t)(b * 4096 + m0 + mm) * 256 + i0 + tx] = t[tx][mm];
}

// ---------------- Theta slots: [0]=th0+th4, [1..3]=th1..3, [4..6]=th5..7 ----------------
__global__ __launch_bounds__(256) void build_theta(const float* __restrict__ th,
                                                   bf16* __restrict__ Tall) {
  int idx = blockIdx.x * 256 + threadIdx.x;  // 7*65536 exactly
  int s = idx >> 16;
  int oi = idx & 65535;
  float v;
  if (s == 0)      v = th[oi * 8 + 0] + th[oi * 8 + 4];
  else if (s <= 3) v = th[oi * 8 + s];
  else             v = th[oi * 8 + s + 1];
  Tall[idx] = __float2bfloat16(v);
}

// ---------------- 128^2 m97-style bt-GEMM (for shallow-K chan GEMMs) ----------------
__device__ __forceinline__ void gemm_bt_tile(const bf16* __restrict__ A,
                                             const bf16* __restrict__ Bm, int K,
                                             bf16* __restrict__ Cb) {
  __shared__ __align__(16) bf16 As[128 * 32];
  __shared__ __align__(16) bf16 Bs[128 * 32];
  const int tid = threadIdx.x;
  const int lane = tid & 63;
  const int w = tid >> 6;
  const int wr = w >> 1, wc = w & 1;

  const int srow = w * 32 + (lane >> 2);
  const int scol = (lane & 3) * 8;
  bf16* ldsA0 = &As[(w * 32 + 0) * 32];
  bf16* ldsA1 = &As[(w * 32 + 16) * 32];
  bf16* ldsB0 = &Bs[(w * 32 + 0) * 32];
  bf16* ldsB1 = &Bs[(w * 32 + 16) * 32];
  const bf16* aptr0 = A + (size_t)srow * K + scol;
  const bf16* aptr1 = A + (size_t)(srow + 16) * K + scol;
  const bf16* bptr0 = Bm + (size_t)srow * K + scol;
  const bf16* bptr1 = Bm + (size_t)(srow + 16) * K + scol;

  f32x4 acc[4][4];
#pragma unroll
  for (int i = 0; i < 4; ++i)
#pragma unroll
    for (int j = 0; j < 4; ++j) acc[i][j] = (f32x4){0.f, 0.f, 0.f, 0.f};

  const int rsel = lane & 15;
  const int ksel = (lane >> 4) * 8;

  for (int kt = 0; kt < K; kt += 32) {
    GLL16(aptr0 + kt, ldsA0);
    GLL16(aptr1 + kt, ldsA1);
    GLL16(bptr0 + kt, ldsB0);
    GLL16(bptr1 + kt, ldsB1);
    __syncthreads();
    bshort8 av[4], bv[4];
#pragma unroll
    for (int m = 0; m < 4; ++m)
      av[m] = *reinterpret_cast<const bshort8*>(&As[(wr * 64 + m * 16 + rsel) * 32 + ksel]);
#pragma unroll
    for (int n = 0; n < 4; ++n)
      bv[n] = *reinterpret_cast<const bshort8*>(&Bs[(wc * 64 + n * 16 + rsel) * 32 + ksel]);
#pragma unroll
    for (int m = 0; m < 4; ++m)
#pragma unroll
      for (int n = 0; n < 4; ++n)
        acc[m][n] = __builtin_amdgcn_mfma_f32_16x16x32_bf16(av[m], bv[n], acc[m][n], 0, 0, 0);
    __syncthreads();
  }

  const int colf = lane & 15;
  const int rowf = (lane >> 4) * 4;
#pragma unroll
  for (int m = 0; m < 4; ++m) {
#pragma unroll
    for (int n = 0; n < 4; ++n) {
      int r0 = wr * 64 + m * 16 + rowf;
      int c = wc * 64 + n * 16 + colf;
#pragma unroll
      for (int r = 0; r < 4; ++r) {
        size_t off = (size_t)(r0 + r) * 4096 + c;
        Cb[off] = __float2bfloat16(acc[m][n][r]);
      }
    }
  }
}

// ---- all channel-mix GEMMs in ONE launch ----
__global__ __launch_bounds__(256) void chan_all(const bf16* __restrict__ Tall,
                                                const bf16* __restrict__ Xt,
                                                bf16* __restrict__ U0,
                                                bf16* __restrict__ U1,
                                                bf16* __restrict__ U2,
                                                bf16* __restrict__ U3) {
  int rt = blockIdx.x;  // 0..1
  int ct = blockIdx.y;  // 0..31
  int z = blockIdx.z;   // 0..55
  int slot, b;
  bf16* Ubuf;
  size_t rowbase;
  if (z < 48) {
    int k = 1 + z / 16;
    int r = z % 16;
    int chain = r >> 3;
    b = r & 7;
    slot = chain ? k + 3 : k;
    Ubuf = (k == 1) ? U1 : ((k == 2) ? U2 : U3);
    rowbase = (size_t)(chain * 2048 + b * 256);
  } else {
    b = z - 48;
    slot = 0;
    Ubuf = U0;
    rowbase = (size_t)b * 256;
  }
  const bf16* A = Tall + (size_t)slot * 65536 + (size_t)rt * 128 * 256;
  const bf16* Bm = Xt + (size_t)b * 4096 * 256 + (size_t)ct * 128 * 256;
  bf16* dst = Ubuf + (rowbase + (size_t)rt * 128) * 4096 + ct * 128;
  gemm_bt_tile(A, Bm, 256, dst);
}

// ================= 256^2 8-phase bt-GEMM, R2-proven skeleton, VAR A/B =================
// VAR 0 (R2-exact, 144us anchor): reads per phase 12/4/4/4; vmcnt(4) at P3,P7 tails
//   (+ last-iter P3 vmcnt(0), closing R2's latent last-iter A-b1 race).
// VAR 1 (balanced-read experiment): same LDS layout, SAME stage slots & barriers;
//   B nf{2,3} read at Q0, nf{0,1} of the NEXT tile read at Q3 from the other LDS
//   buffer into a ping-ponged reg pair (X: buf0 tiles, Y: buf1 tiles; static names).
//   Reads per phase 8/4/4/8. Waits: vmcnt(4) at P2,P5,P7 tails (each drains only
//   >=2-phase-old loads; in-order drain walked for prologue/steady/last iters;
//   last iter: vmcnt(0) at P2).
template <int EPI, int VAR>  // EPI 0: Cb=bf16(acc+Db); 2: rt<8 Cf=acc+Db+bias else Cf2=acc
__global__ __launch_bounds__(512, 2) void gemm256(
    const bf16* __restrict__ Aall, const bf16* __restrict__ B0m,
    const bf16* __restrict__ B1m, bf16* __restrict__ Cb, float* __restrict__ Cf,
    float* __restrict__ Cf2, const bf16* __restrict__ Db,
    const float* __restrict__ bias, int K) {
  const int tid = threadIdx.x;
  const int lane = tid & 63;
  const int w = tid >> 6;          // wave 0..7
  const int wr = w >> 2, wc = w & 3;

  // T1: bijective XCD swizzle, 256 blocks
  int bid = blockIdx.x;
  int gid = (bid & 7) * 32 + (bid >> 3);
  const int rt = gid >> 4, ct = gid & 15;

  const bf16* Atile = Aall + (size_t)rt * 256 * K;
  const bf16* Btile = ((rt < 8) ? B0m : B1m) + (size_t)ct * 256 * K;

  __shared__ __align__(16) char lds_[131072];

  // staging: thread covers rows {srow, srow+64} of a 128-row half; T2 swizzle on src
  const int srow = tid >> 3;
  const int scol = (((tid & 7) ^ (srow & 7)) << 3);  // elements
  const bf16* gA = Atile + (size_t)srow * K + scol;
  const bf16* gB = Btile + (size_t)srow * K + scol;

#define STAGE_A(buf, half, kt)                                                 \
  do {                                                                         \
    char* l = &lds_[(buf)*65536 + (half)*16384 + w * 1024];                    \
    const bf16* g = gA + (size_t)((half)*128) * K + (size_t)(kt)*64;           \
    GLL16(g, l);                                                               \
    GLL16(g + (size_t)64 * K, l + 8192);                                       \
  } while (0)
#define STAGE_B(buf, half, kt)                                                 \
  do {                                                                         \
    char* l = &lds_[(buf)*65536 + 32768 + (half)*16384 + w * 1024];            \
    const bf16* g = gB + (size_t)((half)*128) * K + (size_t)(kt)*64;           \
    GLL16(g, l);                                                               \
    GLL16(g + (size_t)64 * K, l + 8192);                                       \
  } while (0)

  const int rsel = lane & 15;
  const int cbb = lane >> 4;   // 0..3
  const int xorv = rsel & 7;
  const int aBase = wr * 16384 + rsel * 128;
  const int bBase = 32768 + (wc >> 1) * 16384 + ((wc & 1) * 64 + rsel) * 128;
#define LDA(buf, mf, ks)                                                       \
  (*(const bshort8*)&lds_[(buf)*65536 + aBase + (mf)*2048 +                    \
                          (((((ks)*4) + cbb) ^ xorv) << 4)])
#define LDB(buf, nf, ks)                                                       \
  (*(const bshort8*)&lds_[(buf)*65536 + bBase + (nf)*2048 +                    \
                          (((((ks)*4) + cbb) ^ xorv) << 4)])

  f32x4 acc[8][4];
#pragma unroll
  for (int i = 0; i < 8; ++i)
#pragma unroll
    for (int j = 0; j < 4; ++j) acc[i][j] = (f32x4){0.f, 0.f, 0.f, 0.f};

  const int NT = K >> 6;
  const int NI = NT >> 1;

  bshort8 afr[2][2];
  bshort8 bfr[4][2];               // VAR 0
  bshort8 bX[2][2], bY[2][2], bZ[2][2];  // VAR 1

#define RD_A(BUF, Q)                                                           \
  do {                                                                         \
    afr[0][0] = LDA(BUF, (Q)*2 + 0, 0); afr[0][1] = LDA(BUF, (Q)*2 + 0, 1);    \
    afr[1][0] = LDA(BUF, (Q)*2 + 1, 0); afr[1][1] = LDA(BUF, (Q)*2 + 1, 1);    \
  } while (0)
#define RD_B4(BUF)                                                             \
  do {                                                                         \
    bfr[0][0] = LDB(BUF, 0, 0); bfr[0][1] = LDB(BUF, 0, 1);                    \
    bfr[1][0] = LDB(BUF, 1, 0); bfr[1][1] = LDB(BUF, 1, 1);                    \
    bfr[2][0] = LDB(BUF, 2, 0); bfr[2][1] = LDB(BUF, 2, 1);                    \
    bfr[3][0] = LDB(BUF, 3, 0); bfr[3][1] = LDB(BUF, 3, 1);                    \
  } while (0)
#define RD_PAIR(DST, BUF, NF0)                                                 \
  do {                                                                         \
    DST[0][0] = LDB(BUF, NF0, 0);       DST[0][1] = LDB(BUF, NF0, 1);          \
    DST[1][0] = LDB(BUF, (NF0) + 1, 0); DST[1][1] = LDB(BUF, (NF0) + 1, 1);    \
  } while (0)

#define MFMA16A(Q)                                                             \
  do {                                                                         \
    _Pragma("unroll") for (int mi = 0; mi < 2; ++mi)                           \
    _Pragma("unroll") for (int nf = 0; nf < 4; ++nf)                           \
    _Pragma("unroll") for (int ks = 0; ks < 2; ++ks)                           \
        acc[(Q)*2 + mi][nf] = __builtin_amdgcn_mfma_f32_16x16x32_bf16(         \
            afr[mi][ks], bfr[nf][ks], acc[(Q)*2 + mi][nf], 0, 0, 0);           \
  } while (0)
#define MFMA16B(Q, BN)                                                         \
  do {                                                                         \
    _Pragma("unroll") for (int mi = 0; mi < 2; ++mi)                           \
    _Pragma("unroll") for (int ks = 0; ks < 2; ++ks) {                         \
      acc[(Q)*2 + mi][0] = __builtin_amdgcn_mfma_f32_16x16x32_bf16(            \
          afr[mi][ks], BN[0][ks], acc[(Q)*2 + mi][0], 0, 0, 0);                \
      acc[(Q)*2 + mi][1] = __builtin_amdgcn_mfma_f32_16x16x32_bf16(            \
          afr[mi][ks], BN[1][ks], acc[(Q)*2 + mi][1], 0, 0, 0);                \
      acc[(Q)*2 + mi][2] = __builtin_amdgcn_mfma_f32_16x16x32_bf16(            \
          afr[mi][ks], bZ[0][ks], acc[(Q)*2 + mi][2], 0, 0, 0);                \
      acc[(Q)*2 + mi][3] = __builtin_amdgcn_mfma_f32_16x16x32_bf16(            \
          afr[mi][ks], bZ[1][ks], acc[(Q)*2 + mi][3], 0, 0, 0);                \
    }                                                                          \
  } while (0)

#define PHA(BUF, Q, RDB, STAGESTMT, TAILSTMT)                                  \
  do {                                                                         \
    if (RDB) RD_B4(BUF);                                                       \
    RD_A(BUF, Q);                                                              \
    STAGESTMT;                                                                 \
    BARRIER;                                                                   \
    WAIT_LGKM0;                                                                \
    __builtin_amdgcn_s_setprio(1);                                             \
    MFMA16A(Q);                                                                \
    __builtin_amdgcn_s_setprio(0);                                             \
    TAILSTMT;                                                                  \
    BARRIER;                                                                   \
  } while (0)
#define PHB(BUF, Q, BN, EXTRARD, STAGESTMT, TAILSTMT)                          \
  do {                                                                         \
    EXTRARD;                                                                   \
    RD_A(BUF, Q);                                                              \
    STAGESTMT;                                                                 \
    BARRIER;                                                                   \
    WAIT_LGKM0;                                                                \
    __builtin_amdgcn_s_setprio(1);                                             \
    MFMA16B(Q, BN);                                                            \
    __builtin_amdgcn_s_setprio(0);                                             \
    TAILSTMT;                                                                  \
    BARRIER;                                                                   \
  } while (0)

  // prologue: tile0 -> buf0 (B+A), tile1's B -> buf1. vmcnt(4) drains buf0's 8,
  // leaves B-buf1's 4 in flight == steady-state P0-entry invariant.
  STAGE_B(0, 0, 0); STAGE_B(0, 1, 0);
  STAGE_A(0, 0, 0); STAGE_A(0, 1, 0);
  STAGE_B(1, 0, 1); STAGE_B(1, 1, 1);
  WAIT_VM(4);
  BARRIER;
  if constexpr (VAR == 1) { RD_PAIR(bX, 0, 0); }  // preload nf01(buf0,t0)

  for (int it = 0; it < NI; ++it) {
    const int t1 = 2 * it + 1, t2 = 2 * it + 2, t3 = 2 * it + 3;
    const bool p2v = t2 < NT, p3v = t3 < NT, last = (it == NI - 1);
    if constexpr (VAR == 0) {
      PHA(0, 0, 1, { STAGE_A(1, 0, t1); STAGE_A(1, 1, t1); }, {});
      PHA(0, 1, 0, { if (p2v) STAGE_B(0, 0, t2); }, {});
      PHA(0, 2, 0, { if (p2v) STAGE_B(0, 1, t2); }, {});
      PHA(0, 3, 0, {}, { if (last) { WAIT_VM(0); } else { WAIT_VM(4); } });
      PHA(1, 0, 1, { if (p2v) STAGE_A(0, 0, t2); }, {});
      PHA(1, 1, 0, { if (p2v) STAGE_A(0, 1, t2); }, {});
      PHA(1, 2, 0, { if (p3v) STAGE_B(1, 0, t3); }, {});
      PHA(1, 3, 0, { if (p3v) STAGE_B(1, 1, t3); }, { WAIT_VM(4); });
    } else {
      PHB(0, 0, bX, { RD_PAIR(bZ, 0, 2); },
          { STAGE_A(1, 0, t1); STAGE_A(1, 1, t1); }, {});
      PHB(0, 1, bX, {}, { if (p2v) STAGE_B(0, 0, t2); }, {});
      PHB(0, 2, bX, {}, { if (p2v) STAGE_B(0, 1, t2); },
          { if (last) { WAIT_VM(0); } else { WAIT_VM(4); } });
      PHB(0, 3, bX, { RD_PAIR(bY, 1, 0); }, {}, {});
      PHB(1, 0, bY, { RD_PAIR(bZ, 1, 2); }, { if (p2v) STAGE_A(0, 0, t2); }, {});
      PHB(1, 1, bY, {}, { if (p2v) STAGE_A(0, 1, t2); }, { WAIT_VM(4); });
      PHB(1, 2, bY, {}, { if (p3v) STAGE_B(1, 0, t3); }, {});
      PHB(1, 3, bY, { if (!last) RD_PAIR(bX, 0, 0); },
          { if (p3v) STAGE_B(1, 1, t3); }, { WAIT_VM(4); });
    }
  }

  // epilogue: C/D map col=lane&15, row=(lane>>4)*4+reg (verified m89/m91)
  const int colf = lane & 15;
  const int rowf = (lane >> 4) * 4;
  const size_t crow0 = (size_t)rt * 256 + wr * 128;
  const size_t ccol0 = (size_t)ct * 256 + wc * 64;
#pragma unroll
  for (int mf = 0; mf < 8; ++mf) {
#pragma unroll
    for (int nf = 0; nf < 4; ++nf) {
#pragma unroll
      for (int r = 0; r < 4; ++r) {
        size_t row = crow0 + mf * 16 + rowf + r;
        size_t col = ccol0 + nf * 16 + colf;
        size_t off = row * 4096 + col;
        float v = acc[mf][nf][r];
        if constexpr (EPI == 0) {
          v += __bfloat162float(Db[off]);
          Cb[off] = __float2bfloat16(v);
        } else {
          if (rt < 8) {
            v += __bfloat162float(Db[off]) + bias[row & 255];
            Cf[off] = v;
          } else {
            Cf2[(row - 2048) * 4096 + col] = v;
          }
        }
      }
    }
  }
#undef STAGE_A
#undef STAGE_B
#undef LDA
#undef LDB
#undef RD_A
#undef RD_B4
#undef RD_PAIR
#undef MFMA16A
#undef MFMA16B
#undef PHA
#undef PHB
}

// ---- Y += P1 ----
__global__ __launch_bounds__(256) void reduce_add(float* __restrict__ Y,
                                                  const float* __restrict__ P1) {
  float4* Y4 = (float4*)Y;
  const float4* P4 = (const float4*)P1;
  const int n4 = 2048 * 4096 / 4;
  int stride = gridDim.x * blockDim.x;
  for (int i = blockIdx.x * 256 + threadIdx.x; i < n4; i += stride) {
    float4 a = Y4[i];
    float4 b = P4[i];
    a.x += b.x; a.y += b.y; a.z += b.z; a.w += b.w;
    Y4[i] = a;
  }
}

extern "C" void kernel_launch(void* const* d_in, const int* in_sizes, int n_in,
                              void* d_out, int out_size, void* d_ws, size_t ws_size,
                              hipStream_t stream) {
  const float* Ll = (const float*)d_in[0];
  const float* Lu = (const float*)d_in[1];
  const float* x = (const float*)d_in[2];
  const float* th = (const float*)d_in[3];
  const float* bias = (const float*)d_in[4];
  float* Y = (float*)d_out;

  // Workspace: total 235,798,528 B (< proven 252,575,744; R3 showed 269 MB aborts).
  char* ws = (char*)d_ws;
  const size_t SZ_L = (size_t)4096 * 4096 * 2;
  const size_t SZ_U = (size_t)4096 * 4096 * 2;
  const size_t SZ_X = (size_t)8 * 4096 * 256 * 2;
  const size_t SZ_T = ((size_t)7 * 256 * 256 * 2 + 255) & ~(size_t)255;
  const size_t SZ_U0 = (size_t)2048 * 4096 * 2;
  bf16* Llb = (bf16*)ws; ws += SZ_L;
  bf16* Lub = (bf16*)ws; ws += SZ_L;
  bf16* Xt  = (bf16*)ws; ws += SZ_X;
  bf16* Tall = (bf16*)ws; ws += SZ_T;
  bf16* U1 = (bf16*)ws; ws += SZ_U;
  bf16* U2 = (bf16*)ws; ws += SZ_U;
  bf16* U3 = (bf16*)ws; ws += SZ_U;   // reused as V2 output of g2
  bf16* U0 = (bf16*)ws; ws += SZ_U0;
  bf16* V1 = (bf16*)ws; ws += SZ_U;
  // P1 aliases V1 (dead after g2); 2048*4096*4 B == SZ_U exactly.
  float* P1 = (float*)V1;
  (void)ws_size; (void)in_sizes; (void)n_in; (void)out_size;

  cast_f32_bf16<<<2048, 256, 0, stream>>>(Ll, Llb, 4096 * 4096 / 4);
  cast_f32_bf16<<<2048, 256, 0, stream>>>(Lu, Lub, 4096 * 4096 / 4);
  transpose_cast_x<<<dim3(64, 4, 8), 256, 0, stream>>>(x, Xt);
  build_theta<<<1792, 256, 0, stream>>>(th, Tall);

  chan_all<<<dim3(2, 32, 56), 256, 0, stream>>>(Tall, Xt, U0, U1, U2, U3);

  // A/B: g1 = variant A (anchor), g2 = variant B (experiment), g3 = A + EPI2
  gemm256<0, 0><<<256, 512, 0, stream>>>(U3, Llb, Lub, V1, nullptr, nullptr, U2,
                                         nullptr, 4096);  // V1 = L@U3 + U2
  gemm256<0, 1><<<256, 512, 0, stream>>>(V1, Llb, Lub, U3, nullptr, nullptr, U1,
                                         nullptr, 4096);  // V2(=U3) = L@V1 + U1
  gemm256<2, 0><<<256, 512, 0, stream>>>(U3, Llb, Lub, nullptr, Y, P1, U0, bias,
                                         4096);           // Y(chain0)+U0+bias ; P1(chain1)
  reduce_add<<<2048, 256, 0, stream>>>(Y, P1);
}

// Round 8
// 494.754 us; speedup vs baseline: 1.0791x; 1.0791x over previous
//
#include <hip/hip_runtime.h>
#include <hip/hip_bf16.h>

typedef __hip_bfloat16 bf16;
typedef __attribute__((ext_vector_type(8))) short bshort8;  // 8 x bf16 (4 VGPRs)
typedef __attribute__((ext_vector_type(4))) float f32x4;    // MFMA accumulator

#define GLL16(gsrc, ldst)                                                      \
  __builtin_amdgcn_global_load_lds(                                            \
      (const __attribute__((address_space(1))) void*)(gsrc),                   \
      (__attribute__((address_space(3))) void*)(ldst), 16, 0, 0)

#define MEMFENCE asm volatile("" ::: "memory")
#define BARRIER                                                                \
  do {                                                                         \
    MEMFENCE;                                                                  \
    __builtin_amdgcn_s_barrier();                                              \
    MEMFENCE;                                                                  \
  } while (0)
#define WAIT_LGKM0 asm volatile("s_waitcnt lgkmcnt(0)" ::: "memory")
#define WAIT_LGKM8 asm volatile("s_waitcnt lgkmcnt(8)" ::: "memory")
#define WAIT_VM(n) asm volatile("s_waitcnt vmcnt(" #n ")" ::: "memory")

// ---------------- cast f32 -> bf16, vectorized ----------------
__global__ __launch_bounds__(256) void cast_f32_bf16(const float* __restrict__ src,
                                                     bf16* __restrict__ dst, int n4) {
  int stride = gridDim.x * blockDim.x;
  const float4* s4 = reinterpret_cast<const float4*>(src);
  __hip_bfloat162* d2 = reinterpret_cast<__hip_bfloat162*>(dst);
  for (int i = blockIdx.x * blockDim.x + threadIdx.x; i < n4; i += stride) {
    float4 v = s4[i];
    d2[2 * i]     = __float22bfloat162_rn(make_float2(v.x, v.y));
    d2[2 * i + 1] = __float22bfloat162_rn(make_float2(v.z, v.w));
  }
}

// ---------------- x (b,i,m) f32 -> Xt (b,m,i) bf16 ----------------
__global__ __launch_bounds__(256) void transpose_cast_x(const float* __restrict__ x,
                                                        bf16* __restrict__ Xt) {
  __shared__ bf16 t[64][65];
  int b = blockIdx.z;
  int m0 = blockIdx.x * 64;
  int i0 = blockIdx.y * 64;
  int tx = threadIdx.x & 63;
  int ty = threadIdx.x >> 6;
  for (int ii = ty; ii < 64; ii += 4)
    t[ii][tx] = __float2bfloat16(x[(size_t)(b * 256 + i0 + ii) * 4096 + m0 + tx]);
  __syncthreads();
  for (int mm = ty; mm < 64; mm += 4)
    Xt[(size_t)(b * 4096 + m0 + mm) * 256 + i0 + tx] = t[tx][mm];
}

// ---------------- Theta slots: [0]=th0+th4, [1..3]=th1..3, [4..6]=th5..7 ----------------
__global__ __launch_bounds__(256) void build_theta(const float* __restrict__ th,
                                                   bf16* __restrict__ Tall) {
  int idx = blockIdx.x * 256 + threadIdx.x;  // 7*65536 exactly
  int s = idx >> 16;
  int oi = idx & 65535;
  float v;
  if (s == 0)      v = th[oi * 8 + 0] + th[oi * 8 + 4];
  else if (s <= 3) v = th[oi * 8 + s];
  else             v = th[oi * 8 + s + 1];
  Tall[idx] = __float2bfloat16(v);
}

// ---------------- 128^2 m97-style bt-GEMM (for shallow-K chan GEMMs) ----------------
__device__ __forceinline__ void gemm_bt_tile(const bf16* __restrict__ A,
                                             const bf16* __restrict__ Bm, int K,
                                             bf16* __restrict__ Cb) {
  __shared__ __align__(16) bf16 As[128 * 32];
  __shared__ __align__(16) bf16 Bs[128 * 32];
  const int tid = threadIdx.x;
  const int lane = tid & 63;
  const int w = tid >> 6;
  const int wr = w >> 1, wc = w & 1;

  const int srow = w * 32 + (lane >> 2);
  const int scol = (lane & 3) * 8;
  bf16* ldsA0 = &As[(w * 32 + 0) * 32];
  bf16* ldsA1 = &As[(w * 32 + 16) * 32];
  bf16* ldsB0 = &Bs[(w * 32 + 0) * 32];
  bf16* ldsB1 = &Bs[(w * 32 + 16) * 32];
  const bf16* aptr0 = A + (size_t)srow * K + scol;
  const bf16* aptr1 = A + (size_t)(srow + 16) * K + scol;
  const bf16* bptr0 = Bm + (size_t)srow * K + scol;
  const bf16* bptr1 = Bm + (size_t)(srow + 16) * K + scol;

  f32x4 acc[4][4];
#pragma unroll
  for (int i = 0; i < 4; ++i)
#pragma unroll
    for (int j = 0; j < 4; ++j) acc[i][j] = (f32x4){0.f, 0.f, 0.f, 0.f};

  const int rsel = lane & 15;
  const int ksel = (lane >> 4) * 8;

  for (int kt = 0; kt < K; kt += 32) {
    GLL16(aptr0 + kt, ldsA0);
    GLL16(aptr1 + kt, ldsA1);
    GLL16(bptr0 + kt, ldsB0);
    GLL16(bptr1 + kt, ldsB1);
    __syncthreads();
    bshort8 av[4], bv[4];
#pragma unroll
    for (int m = 0; m < 4; ++m)
      av[m] = *reinterpret_cast<const bshort8*>(&As[(wr * 64 + m * 16 + rsel) * 32 + ksel]);
#pragma unroll
    for (int n = 0; n < 4; ++n)
      bv[n] = *reinterpret_cast<const bshort8*>(&Bs[(wc * 64 + n * 16 + rsel) * 32 + ksel]);
#pragma unroll
    for (int m = 0; m < 4; ++m)
#pragma unroll
      for (int n = 0; n < 4; ++n)
        acc[m][n] = __builtin_amdgcn_mfma_f32_16x16x32_bf16(av[m], bv[n], acc[m][n], 0, 0, 0);
    __syncthreads();
  }

  const int colf = lane & 15;
  const int rowf = (lane >> 4) * 4;
#pragma unroll
  for (int m = 0; m < 4; ++m) {
#pragma unroll
    for (int n = 0; n < 4; ++n) {
      int r0 = wr * 64 + m * 16 + rowf;
      int c = wc * 64 + n * 16 + colf;
#pragma unroll
      for (int r = 0; r < 4; ++r) {
        size_t off = (size_t)(r0 + r) * 4096 + c;
        Cb[off] = __float2bfloat16(acc[m][n][r]);
      }
    }
  }
}

// ---- all channel-mix GEMMs in ONE launch ----
__global__ __launch_bounds__(256) void chan_all(const bf16* __restrict__ Tall,
                                                const bf16* __restrict__ Xt,
                                                bf16* __restrict__ U0,
                                                bf16* __restrict__ U1,
                                                bf16* __restrict__ U2,
                                                bf16* __restrict__ U3) {
  int rt = blockIdx.x;  // 0..1
  int ct = blockIdx.y;  // 0..31
  int z = blockIdx.z;   // 0..55
  int slot, b;
  bf16* Ubuf;
  size_t rowbase;
  if (z < 48) {
    int k = 1 + z / 16;
    int r = z % 16;
    int chain = r >> 3;
    b = r & 7;
    slot = chain ? k + 3 : k;
    Ubuf = (k == 1) ? U1 : ((k == 2) ? U2 : U3);
    rowbase = (size_t)(chain * 2048 + b * 256);
  } else {
    b = z - 48;
    slot = 0;
    Ubuf = U0;
    rowbase = (size_t)b * 256;
  }
  const bf16* A = Tall + (size_t)slot * 65536 + (size_t)rt * 128 * 256;
  const bf16* Bm = Xt + (size_t)b * 4096 * 256 + (size_t)ct * 128 * 256;
  bf16* dst = Ubuf + (rowbase + (size_t)rt * 128) * 4096 + ct * 128;
  gemm_bt_tile(A, Bm, 256, dst);
}

// ================= 256^2 8-phase bt-GEMM (R2 interior + loop peel + lgkm8) =================
// C(256x256) = A(256xK) * B(256xK)^T-rows, ldc=4096. 8 waves (2Mx4N), per-wave 128x64.
// LDS 128KiB: buf{0,1} x {A-h0,A-h1,B-h0,B-h1} x 16KB. T2 swizzle (16B col-block ^= row&7),
// pre-swizzled global source + swizzled ds_read (involution, rule #21).
// Per phase: [12 or 4 ds_reads] [stage] [lgkm8 if 12 reads] BAR lgkm0 setprio1 16xMFMA
// setprio0 [vmcnt tail] BAR. Stage slots (iter; t1=2it+1,t2=2it+2,t3=2it+3):
// P0:A(b1,t1)x2 P1:B(0,0,t2) P2:B(0,1,t2) P3:- vmcnt(4) P4:A(0,0,t2) P5:A(0,1,t2)
// P6:B(1,0,t3) P7:B(1,1,t3) vmcnt(4). Steady loop (it<NI-1) has NO branches (predicates
// provably true); last iteration peeled: only P0 stages A(b1,last), vmcnt(0) at P3
// (fixes R2's latent last-iter race). Drain walk verified prologue/steady/last.
template <int EPI>  // 0: Cb=bf16(acc+Db) ; 2: rt<8 -> Cf=acc+Db+bias (Y), rt>=8 -> Cf2=acc (P1)
__global__ __launch_bounds__(512, 2) void gemm256(
    const bf16* __restrict__ Aall, const bf16* __restrict__ B0m,
    const bf16* __restrict__ B1m, bf16* __restrict__ Cb, float* __restrict__ Cf,
    float* __restrict__ Cf2, const bf16* __restrict__ Db,
    const float* __restrict__ bias, int K) {
  const int tid = threadIdx.x;
  const int lane = tid & 63;
  const int w = tid >> 6;          // wave 0..7
  const int wr = w >> 2, wc = w & 3;

  // T1: bijective XCD swizzle, 256 blocks
  int bid = blockIdx.x;
  int gid = (bid & 7) * 32 + (bid >> 3);
  const int rt = gid >> 4, ct = gid & 15;

  const bf16* Atile = Aall + (size_t)rt * 256 * K;
  const bf16* Btile = ((rt < 8) ? B0m : B1m) + (size_t)ct * 256 * K;

  __shared__ __align__(16) char lds_[131072];

  // staging: thread covers rows {srow, srow+64} of a 128-row half; T2 swizzle on src
  const int srow = tid >> 3;
  const int scol = (((tid & 7) ^ (srow & 7)) << 3);  // elements
  const bf16* gA = Atile + (size_t)srow * K + scol;
  const bf16* gB = Btile + (size_t)srow * K + scol;

#define STAGE_A(buf, half, kt)                                                 \
  do {                                                                         \
    char* l = &lds_[(buf)*65536 + (half)*16384 + w * 1024];                    \
    const bf16* g = gA + (size_t)((half)*128) * K + (size_t)(kt)*64;           \
    GLL16(g, l);                                                               \
    GLL16(g + (size_t)64 * K, l + 8192);                                       \
  } while (0)
#define STAGE_B(buf, half, kt)                                                 \
  do {                                                                         \
    char* l = &lds_[(buf)*65536 + 32768 + (half)*16384 + w * 1024];            \
    const bf16* g = gB + (size_t)((half)*128) * K + (size_t)(kt)*64;           \
    GLL16(g, l);                                                               \
    GLL16(g + (size_t)64 * K, l + 8192);                                       \
  } while (0)

  const int rsel = lane & 15;
  const int cbb = lane >> 4;   // 0..3
  const int xorv = rsel & 7;
  const int aBase = wr * 16384 + rsel * 128;
  const int bBase = 32768 + (wc >> 1) * 16384 + ((wc & 1) * 64 + rsel) * 128;
#define LDA(buf, mf, ks)                                                       \
  (*(const bshort8*)&lds_[(buf)*65536 + aBase + (mf)*2048 +                    \
                          (((((ks)*4) + cbb) ^ xorv) << 4)])
#define LDB(buf, nf, ks)                                                       \
  (*(const bshort8*)&lds_[(buf)*65536 + bBase + (nf)*2048 +                    \
                          (((((ks)*4) + cbb) ^ xorv) << 4)])

  f32x4 acc[8][4];
#pragma unroll
  for (int i = 0; i < 8; ++i)
#pragma unroll
    for (int j = 0; j < 4; ++j) acc[i][j] = (f32x4){0.f, 0.f, 0.f, 0.f};

  const int NT = K >> 6;
  const int NI = NT >> 1;

  bshort8 afr[2][2];
  bshort8 bfr[4][2];

#define RD_A(BUF, Q)                                                           \
  do {                                                                         \
    afr[0][0] = LDA(BUF, (Q)*2 + 0, 0); afr[0][1] = LDA(BUF, (Q)*2 + 0, 1);    \
    afr[1][0] = LDA(BUF, (Q)*2 + 1, 0); afr[1][1] = LDA(BUF, (Q)*2 + 1, 1);    \
  } while (0)
#define RD_B4(BUF)                                                             \
  do {                                                                         \
    bfr[0][0] = LDB(BUF, 0, 0); bfr[0][1] = LDB(BUF, 0, 1);                    \
    bfr[1][0] = LDB(BUF, 1, 0); bfr[1][1] = LDB(BUF, 1, 1);                    \
    bfr[2][0] = LDB(BUF, 2, 0); bfr[2][1] = LDB(BUF, 2, 1);                    \
    bfr[3][0] = LDB(BUF, 3, 0); bfr[3][1] = LDB(BUF, 3, 1);                    \
  } while (0)

#define MFMA16(Q)                                                              \
  do {                                                                         \
    _Pragma("unroll") for (int mi = 0; mi < 2; ++mi)                           \
    _Pragma("unroll") for (int nf = 0; nf < 4; ++nf)                           \
    _Pragma("unroll") for (int ks = 0; ks < 2; ++ks)                           \
        acc[(Q)*2 + mi][nf] = __builtin_amdgcn_mfma_f32_16x16x32_bf16(         \
            afr[mi][ks], bfr[nf][ks], acc[(Q)*2 + mi][nf], 0, 0, 0);           \
  } while (0)

#define PHA(BUF, Q, RDB, STAGESTMT, TAILSTMT)                                  \
  do {                                                                         \
    if (RDB) RD_B4(BUF);                                                       \
    RD_A(BUF, Q);                                                              \
    STAGESTMT;                                                                 \
    if (RDB) WAIT_LGKM8;                                                       \
    BARRIER;                                                                   \
    WAIT_LGKM0;                                                                \
    __builtin_amdgcn_s_setprio(1);                                             \
    MFMA16(Q);                                                                 \
    __builtin_amdgcn_s_setprio(0);                                             \
    TAILSTMT;                                                                  \
    BARRIER;                                                                   \
  } while (0)

  // prologue: tile0 -> buf0 (B+A), tile1's B -> buf1. vmcnt(4) drains buf0's 8,
  // leaves B-buf1's 4 in flight == steady-state P0-entry invariant.
  STAGE_B(0, 0, 0); STAGE_B(0, 1, 0);
  STAGE_A(0, 0, 0); STAGE_A(0, 1, 0);
  STAGE_B(1, 0, 1); STAGE_B(1, 1, 1);
  WAIT_VM(4);
  BARRIER;

  // steady iterations: stages unconditional (t1,t2 <= NT-2, t3 <= NT-1 for it <= NI-2)
  for (int it = 0; it < NI - 1; ++it) {
    const int t1 = 2 * it + 1, t2 = 2 * it + 2, t3 = 2 * it + 3;
    PHA(0, 0, 1, { STAGE_A(1, 0, t1); STAGE_A(1, 1, t1); }, {});
    PHA(0, 1, 0, { STAGE_B(0, 0, t2); }, {});
    PHA(0, 2, 0, { STAGE_B(0, 1, t2); }, {});
    PHA(0, 3, 0, {}, { WAIT_VM(4); });
    PHA(1, 0, 1, { STAGE_A(0, 0, t2); }, {});
    PHA(1, 1, 0, { STAGE_A(0, 1, t2); }, {});
    PHA(1, 2, 0, { STAGE_B(1, 0, t3); }, {});
    PHA(1, 3, 0, { STAGE_B(1, 1, t3); }, { WAIT_VM(4); });
  }
  // peeled last iteration: only the A(b1) stage remains; vmcnt(0) at P3 closes the race.
  {
    const int tl = NT - 1;
    PHA(0, 0, 1, { STAGE_A(1, 0, tl); STAGE_A(1, 1, tl); }, {});
    PHA(0, 1, 0, {}, {});
    PHA(0, 2, 0, {}, {});
    PHA(0, 3, 0, {}, { WAIT_VM(0); });
    PHA(1, 0, 1, {}, {});
    PHA(1, 1, 0, {}, {});
    PHA(1, 2, 0, {}, {});
    PHA(1, 3, 0, {}, {});
  }

  // epilogue: C/D map col=lane&15, row=(lane>>4)*4+reg (verified m89/m91)
  const int colf = lane & 15;
  const int rowf = (lane >> 4) * 4;
  const size_t crow0 = (size_t)rt * 256 + wr * 128;
  const size_t ccol0 = (size_t)ct * 256 + wc * 64;
#pragma unroll
  for (int mf = 0; mf < 8; ++mf) {
#pragma unroll
    for (int nf = 0; nf < 4; ++nf) {
#pragma unroll
      for (int r = 0; r < 4; ++r) {
        size_t row = crow0 + mf * 16 + rowf + r;
        size_t col = ccol0 + nf * 16 + colf;
        size_t off = row * 4096 + col;
        float v = acc[mf][nf][r];
        if constexpr (EPI == 0) {
          v += __bfloat162float(Db[off]);
          Cb[off] = __float2bfloat16(v);
        } else {
          if (rt < 8) {
            v += __bfloat162float(Db[off]) + bias[row & 255];
            Cf[off] = v;
          } else {
            Cf2[(row - 2048) * 4096 + col] = v;
          }
        }
      }
    }
  }
#undef STAGE_A
#undef STAGE_B
#undef LDA
#undef LDB
#undef RD_A
#undef RD_B4
#undef MFMA16
#undef PHA
}

// ---- Y += P1 ----
__global__ __launch_bounds__(256) void reduce_add(float* __restrict__ Y,
                                                  const float* __restrict__ P1) {
  float4* Y4 = (float4*)Y;
  const float4* P4 = (const float4*)P1;
  const int n4 = 2048 * 4096 / 4;
  int stride = gridDim.x * blockDim.x;
  for (int i = blockIdx.x * 256 + threadIdx.x; i < n4; i += stride) {
    float4 a = Y4[i];
    float4 b = P4[i];
    a.x += b.x; a.y += b.y; a.z += b.z; a.w += b.w;
    Y4[i] = a;
  }
}

extern "C" void kernel_launch(void* const* d_in, const int* in_sizes, int n_in,
                              void* d_out, int out_size, void* d_ws, size_t ws_size,
                              hipStream_t stream) {
  const float* Ll = (const float*)d_in[0];
  const float* Lu = (const float*)d_in[1];
  const float* x = (const float*)d_in[2];
  const float* th = (const float*)d_in[3];
  const float* bias = (const float*)d_in[4];
  float* Y = (float*)d_out;

  // Workspace: total 235,798,528 B (< proven 252,575,744; 269 MB aborted in R3).
  char* ws = (char*)d_ws;
  const size_t SZ_L = (size_t)4096 * 4096 * 2;
  const size_t SZ_U = (size_t)4096 * 4096 * 2;
  const size_t SZ_X = (size_t)8 * 4096 * 256 * 2;
  const size_t SZ_T = ((size_t)7 * 256 * 256 * 2 + 255) & ~(size_t)255;
  const size_t SZ_U0 = (size_t)2048 * 4096 * 2;
  bf16* Llb = (bf16*)ws; ws += SZ_L;
  bf16* Lub = (bf16*)ws; ws += SZ_L;
  bf16* Xt  = (bf16*)ws; ws += SZ_X;
  bf16* Tall = (bf16*)ws; ws += SZ_T;
  bf16* U1 = (bf16*)ws; ws += SZ_U;
  bf16* U2 = (bf16*)ws; ws += SZ_U;
  bf16* U3 = (bf16*)ws; ws += SZ_U;   // reused as V2 output of g2
  bf16* U0 = (bf16*)ws; ws += SZ_U0;
  bf16* V1 = (bf16*)ws; ws += SZ_U;
  // P1 aliases V1 (dead after g2); 2048*4096*4 B == SZ_U exactly.
  float* P1 = (float*)V1;
  (void)ws_size; (void)in_sizes; (void)n_in; (void)out_size;

  cast_f32_bf16<<<2048, 256, 0, stream>>>(Ll, Llb, 4096 * 4096 / 4);
  cast_f32_bf16<<<2048, 256, 0, stream>>>(Lu, Lub, 4096 * 4096 / 4);
  transpose_cast_x<<<dim3(64, 4, 8), 256, 0, stream>>>(x, Xt);
  build_theta<<<1792, 256, 0, stream>>>(th, Tall);

  chan_all<<<dim3(2, 32, 56), 256, 0, stream>>>(Tall, Xt, U0, U1, U2, U3);

  gemm256<0><<<256, 512, 0, stream>>>(U3, Llb, Lub, V1, nullptr, nullptr, U2,
                                      nullptr, 4096);  // V1 = L@U3 + U2
  gemm256<0><<<256, 512, 0, stream>>>(V1, Llb, Lub, U3, nullptr, nullptr, U1,
                                      nullptr, 4096);  // V2(=U3) = L@V1 + U1
  gemm256<2><<<256, 512, 0, stream>>>(U3, Llb, Lub, nullptr, Y, P1, U0, bias,
                                      4096);           // Y(chain0)+U0+bias ; P1(chain1)
  reduce_add<<<2048, 256, 0, stream>>>(Y, P1);
}